// Round 12
// baseline (2556.193 us; speedup 1.0000x reference)
//
#include <hip/hip_runtime.h>
#include <math.h>

// Problem constants
constexpr int kB  = 8;
constexpr int kS  = 256;
constexpr int kH  = 768;
constexpr int kNL = 12;
constexpr int kNH = 12;
constexpr int kFF = 3072;
constexpr int kC  = 9;
constexpr int kDH = 64;
constexpr int kM  = kB * kS;   // 2048 tokens
constexpr size_t kMH = (size_t)kM * kH;      // 1,572,864
constexpr size_t kHH = (size_t)kH * kH;      // 589,824
constexpr size_t kHF = (size_t)kH * kFF;     // 2,359,296
constexpr unsigned kMagic = 0x7A3B19C5u;

typedef float f32x4 __attribute__((ext_vector_type(4)));
typedef _Float16 f16;
typedef _Float16 f16x4 __attribute__((ext_vector_type(4)));
typedef _Float16 f16x8 __attribute__((ext_vector_type(8)));

#define GLL16(gp, lp)                                                   \
  __builtin_amdgcn_global_load_lds(                                     \
      (const __attribute__((address_space(1))) void*)(gp),              \
      (__attribute__((address_space(3))) void*)(lp), 16, 0, 0)

// ---------------------------------------------------------------------------
// Fused embedding + LayerNorm: h = LN(we[x]+pe+te); emits fp32 + fp16 plane.
// ---------------------------------------------------------------------------
__global__ __launch_bounds__(256) void embed_ln_kernel(
    const int* __restrict__ x, const float* __restrict__ we,
    const float* __restrict__ pe, const float* __restrict__ te,
    const float* __restrict__ w, const float* __restrict__ b,
    float* __restrict__ hout, f16* __restrict__ hHf) {
  int tok = blockIdx.x, tid = threadIdx.x;
  int wid = x[tok];
  int sI = tok & (kS - 1);
  __shared__ float red[8];
  float vals[3];
  float s = 0.f, s2 = 0.f;
#pragma unroll
  for (int j = 0; j < 3; j++) {
    int c = tid + j * 256;
    float v = we[(size_t)wid * kH + c] + pe[sI * kH + c] + te[c];
    vals[j] = v;
    s += v; s2 += v * v;
  }
#pragma unroll
  for (int o = 32; o > 0; o >>= 1) {
    s  += __shfl_down(s, o, 64);
    s2 += __shfl_down(s2, o, 64);
  }
  int lane = tid & 63, wv = tid >> 6;
  if (lane == 0) { red[wv] = s; red[4 + wv] = s2; }
  __syncthreads();
  float sum   = red[0] + red[1] + red[2] + red[3];
  float sumsq = red[4] + red[5] + red[6] + red[7];
  float mean = sum / kH;
  float var  = sumsq / kH - mean * mean;
  float inv  = rsqrtf(var + 1e-12f);
#pragma unroll
  for (int j = 0; j < 3; j++) {
    int c = tid + j * 256;
    float ov = (vals[j] - mean) * inv * w[c] + b[c];
    hout[(size_t)tok * kH + c] = ov;
    hHf[(size_t)tok * kH + c] = (f16)ov;
  }
}

// ---------------------------------------------------------------------------
// Fused residual(P f16 partial slabs) + LayerNorm; emits fp32 + fp16 plane.
// EMIS=1: also computes emissions em[tok][9] = LN_out . cls_w + cls_b.
// ---------------------------------------------------------------------------
template <int P, int EMIS>
__global__ __launch_bounds__(256) void addln_kernel(
    const float* __restrict__ hin, const f16* __restrict__ res,
    const float* __restrict__ w, const float* __restrict__ b,
    float* __restrict__ hout, f16* __restrict__ hHf,
    const float* __restrict__ cw, const float* __restrict__ cb,
    float* __restrict__ em) {
  int tok = blockIdx.x, tid = threadIdx.x;
  __shared__ float red[8];
  __shared__ float redE[4 * kC];
  float vals[3];
  float s = 0.f, s2 = 0.f;
#pragma unroll
  for (int j = 0; j < 3; j++) {
    int c = tid + j * 256;
    float v = hin[(size_t)tok * kH + c];
#pragma unroll
    for (int p = 0; p < P; p++) v += (float)res[p * kMH + (size_t)tok * kH + c];
    vals[j] = v;
    s += v; s2 += v * v;
  }
#pragma unroll
  for (int o = 32; o > 0; o >>= 1) {
    s  += __shfl_down(s, o, 64);
    s2 += __shfl_down(s2, o, 64);
  }
  int lane = tid & 63, wv = tid >> 6;
  if (lane == 0) { red[wv] = s; red[4 + wv] = s2; }
  __syncthreads();
  float sum   = red[0] + red[1] + red[2] + red[3];
  float sumsq = red[4] + red[5] + red[6] + red[7];
  float mean = sum / kH;
  float var  = sumsq / kH - mean * mean;
  float inv  = rsqrtf(var + 1e-12f);
  float acc9[EMIS ? kC : 1];
  if (EMIS) {
#pragma unroll
    for (int c = 0; c < kC; ++c) acc9[c] = 0.f;
  }
#pragma unroll
  for (int j = 0; j < 3; j++) {
    int c = tid + j * 256;
    float ov = (vals[j] - mean) * inv * w[c] + b[c];
    hout[(size_t)tok * kH + c] = ov;
    hHf[(size_t)tok * kH + c] = (f16)ov;
    if (EMIS) {
#pragma unroll
      for (int cls = 0; cls < kC; ++cls) acc9[cls] += ov * cw[c * kC + cls];
    }
  }
  if (EMIS) {
#pragma unroll
    for (int cls = 0; cls < kC; ++cls) {
      float v = acc9[cls];
#pragma unroll
      for (int o = 32; o > 0; o >>= 1) v += __shfl_down(v, o, 64);
      if (lane == 0) redE[wv * kC + cls] = v;
    }
    __syncthreads();
    if (tid < kC) {
      em[(size_t)tok * kC + tid] = redE[tid] + redE[kC + tid] +
                                   redE[2 * kC + tid] + redE[3 * kC + tid] +
                                   cb[tid];
    }
  }
}

// ---------------------------------------------------------------------------
// Weight conversion into TILED cache:
// cache[kt][n][p*8+j] = W[kt*32+(p^s(n))*8+j][n], s(n) = (n>>1)&3.
// ---------------------------------------------------------------------------
constexpr size_t kLStride = 4 * kHH + 2 * kHF;   // 7,077,888 f16

struct WTile {
  const float* src;
  f16* dd;
  int N, kt, n0;
};

__device__ __forceinline__ void wc_resolve(
    int tt, int l0, const float* qkv_w, const float* aow,
    const float* f1w, const float* f2w, f16* wc, WTile& ti) {
  const int perLayer = 3456;   // 864 qkv + 288 attn + 1152 ffn1 + 1152 ffn2
  int li = tt / perLayer, r = tt % perLayer;
  int l = l0 + li;
  f16* base = wc + (size_t)li * kLStride;
  int tn;
  if (r < 864) {
    int m = r / 288; tn = r % 288; ti.N = kH;
    ti.src = qkv_w + ((size_t)l * 3 + m) * kHH;
    ti.dd = base + (size_t)m * kHH;
  } else if (r < 1152) {
    tn = r - 864; ti.N = kH;
    ti.src = aow + (size_t)l * kHH;
    ti.dd = base + 3 * kHH;
  } else if (r < 2304) {
    tn = r - 1152; ti.N = kFF;
    ti.src = f1w + (size_t)l * kHF;
    ti.dd = base + 4 * kHH;
  } else {
    tn = r - 2304; ti.N = kH;
    ti.src = f2w + (size_t)l * kHF;
    ti.dd = base + 4 * kHH + kHF;
  }
  int ntile = ti.N >> 6;
  ti.kt = tn / ntile;
  ti.n0 = (tn % ntile) * 64;
}

__global__ __launch_bounds__(256) void wconv_mega(
    const float* __restrict__ qkv_w, const float* __restrict__ aow,
    const float* __restrict__ f1w, const float* __restrict__ f2w,
    f16* __restrict__ wc, const unsigned* __restrict__ flag,
    int l0, int nl) {
  if (flag && flag[0] == kMagic) return;
  __shared__ float tb[2][32 * 64];   // two linear [32][64] fp32 tiles (16 KB)
  int tid = threadIdx.x;
  int lane = tid & 63, w = tid >> 6;
  int total = nl * 3456;
  int tt = blockIdx.x;
  if (tt >= total) return;
  int G = gridDim.x;

  auto issue = [&](const WTile& ti, int buf) {
#pragma unroll
    for (int sub = 0; sub < 2; ++sub) {
      int u = w * 2 + sub;
      const float* gp = ti.src +
          (size_t)(ti.kt * 32 + u * 4 + (lane >> 4)) * ti.N +
          ti.n0 + (lane & 15) * 4;
      GLL16(gp, &tb[buf][u * 256]);
    }
  };

  WTile cur;
  wc_resolve(tt, l0, qkv_w, aow, f1w, f2w, wc, cur);
  issue(cur, 0);
  int bufc = 0;

  while (true) {
    int ttn = tt + G;
    bool has = ttn < total;
    WTile nxt;
    if (has) {
      wc_resolve(ttn, l0, qkv_w, aow, f1w, f2w, wc, nxt);
      issue(nxt, bufc ^ 1);                 // next tile's loads stay in flight
      asm volatile("s_waitcnt vmcnt(2)" ::: "memory");   // cur's 2 loads done
    } else {
      asm volatile("s_waitcnt vmcnt(0)" ::: "memory");
    }
    __builtin_amdgcn_s_barrier();           // all waves' cur-tile LDS visible
    __builtin_amdgcn_sched_barrier(0);

    {
      int n = tid >> 2, p = tid & 3;
      int s = ((cur.n0 + n) >> 1) & 3;
      int cg = p ^ s;
      f16x8 hv;
#pragma unroll
      for (int j = 0; j < 8; ++j) hv[j] = (f16)tb[bufc][(cg * 8 + j) * 64 + n];
      *(f16x8*)(cur.dd + (size_t)cur.kt * cur.N * 32 +
                (size_t)(cur.n0 + n) * 32 + p * 8) = hv;
    }
    __builtin_amdgcn_sched_barrier(0);
    __builtin_amdgcn_s_barrier();           // emit done before buf reuse
    if (!has) break;
    cur = nxt;
    bufc ^= 1;
    tt = ttn;
  }
}

__global__ void setflag_kernel(unsigned* flag) { flag[0] = kMagic; }

// ---------------------------------------------------------------------------
// fp16 MFMA GEMM (round-7 verified single-buffer structure).
// MODE 0: + GELU, f16 out [M][N].
// MODE 1: qkv — gridDim.z = 3*nspl; z -> (matrix m = z/nspl, kch = z%nspl);
//         f16 head-major slab (kch*3+m)*kMH; bias at kch==0.
// MODE 2: split-K P=gridDim.z; f16 partial slab z*kMH; bias at z==0.
// ---------------------------------------------------------------------------
template <int MODE, int TN>
__global__ __launch_bounds__(256) void gemm_mfma(
    const f16* __restrict__ Af, const f16* __restrict__ W0,
    const float* __restrict__ bias0, f16* __restrict__ outH, int N, int K) {
  constexpr int FN = TN / 32;
  int bx = blockIdx.x, by = blockIdx.y, bz = blockIdx.z;
  const f16* Bf = W0;
  const float* bias = bias0;
  int kt0 = 0, ksteps = K >> 5;
  f16* oH = outH;
  if (MODE == 1) {
    int nspl = gridDim.z / 3;
    int m = bz / nspl, kch = bz % nspl;
    ksteps = (K >> 5) / nspl;
    kt0 = kch * ksteps;
    Bf = W0 + (size_t)m * K * N;
    bias = (kch == 0) ? bias0 + m * N : nullptr;
    oH = outH + (size_t)(kch * 3 + m) * kMH;
  } else if (MODE == 2) {
    int P = gridDim.z;
    ksteps = (K >> 5) / P;
    kt0 = bz * ksteps;
    oH = outH + (size_t)bz * kMH;
    if (bz != 0) bias = nullptr;
  }

  __shared__ f16 ldsA[128 * 32];
  __shared__ f16 ldsB[TN * 32];

  int tid = threadIdx.x;
  int w = tid >> 6, lane = tid & 63;
  int wm = w >> 1, wn = w & 1;

  f32x4 acc[4][FN] = {};

  for (int kt = 0; kt < ksteps; ++kt) {
    int ktAbs = kt0 + kt;
    int kbase = ktAbs * 32;
#pragma unroll
    for (int sub = 0; sub < 2; ++sub) {
      int uu = w * 2 + sub;
      int r = uu * 16 + (lane >> 2);
      int p = lane & 3;
      int c = p ^ ((r >> 1) & 3);
      const f16* gp = Af + (size_t)(by * 128 + r) * K + kbase + c * 8;
      GLL16(gp, &ldsA[uu * 512]);
    }
#pragma unroll
    for (int sub = 0; sub < TN / 64; ++sub) {
      int uu = w * (TN / 64) + sub;
      const f16* gp = Bf + (size_t)ktAbs * N * 32 +
                      ((size_t)bx * TN + uu * 16) * 32 + lane * 8;
      GLL16(gp, &ldsB[uu * 512]);
    }
    __syncthreads();

    f16x8 bfr[FN];
#pragma unroll
    for (int fn = 0; fn < FN; ++fn) {
      int row = wn * (TN / 2) + fn * 16 + (lane & 15);
      int ch = lane >> 4;
      bfr[fn] = *(const f16x8*)&ldsB[row * 32 + (ch ^ ((row >> 1) & 3)) * 8];
    }
#pragma unroll
    for (int fm = 0; fm < 4; ++fm) {
      int row = wm * 64 + fm * 16 + (lane & 15);
      int ch = lane >> 4;
      f16x8 ah = *(const f16x8*)&ldsA[row * 32 + (ch ^ ((row >> 1) & 3)) * 8];
#pragma unroll
      for (int fn = 0; fn < FN; ++fn)
        acc[fm][fn] = __builtin_amdgcn_mfma_f32_16x16x32_f16(ah, bfr[fn], acc[fm][fn], 0, 0, 0);
    }
    __syncthreads();
  }

#pragma unroll
  for (int fm = 0; fm < 4; ++fm) {
#pragma unroll
    for (int fn = 0; fn < FN; ++fn) {
#pragma unroll
      for (int j = 0; j < 4; ++j) {
        int m = by * 128 + wm * 64 + fm * 16 + (lane >> 4) * 4 + j;
        int n = bx * TN + wn * (TN / 2) + fn * 16 + (lane & 15);
        float cv = acc[fm][fn][j];
        if (MODE == 0) {
          cv += bias[n];
          float inner = 0.7978845608028654f * (cv + 0.044715f * cv * cv * cv);
          cv = 0.5f * cv * (1.0f + tanhf(inner));
          oH[(size_t)m * N + n] = (f16)cv;
        } else if (MODE == 1) {
          if (bias) cv += bias[n];
          int b = m >> 8, s = m & 255, hd = n >> 6, dh = n & 63;
          oH[((size_t)(b * kNH + hd) * kS + s) * kDH + dh] = (f16)cv;
        } else {
          if (bias) cv += bias[n];
          oH[(size_t)m * N + n] = (f16)cv;
        }
      }
    }
  }
}

// ---------------------------------------------------------------------------
// Split-KV flash attention, stage 1. grid (96, 4, 4), 256 threads.
// q/k/v f16 head-major DUAL slabs (partial at +3*kMH, summed in fp32).
// K/V staged fp32 in LDS; writes UNNORMALIZED f16 partial ctx + (m, l).
// ---------------------------------------------------------------------------
__global__ __launch_bounds__(256) void attn_part_kernel(
    const f16* __restrict__ qh, const f16* __restrict__ kh,
    const f16* __restrict__ vh, f16* __restrict__ ctxP,
    float* __restrict__ mlM, float* __restrict__ mlL) {
  const size_t DOF = 3 * kMH;
  int bh = blockIdx.x;            // 0..95
  int qtb = blockIdx.y;           // 0..3
  int kvc = blockIdx.z;           // 0..3
  int bb = bh / kNH, hh = bh % kNH;
  int tid = threadIdx.x;
  int part = tid & 3;
  int q = tid >> 2;
  int qg = qtb * 64 + q;

  __shared__ float4 Ks4[64][16];
  __shared__ float4 Vs4[64][16];

  const f16* qp = qh + ((size_t)(bh * kS + qg)) * kDH + part * 16;
  f16x8 qlo = *(const f16x8*)qp;
  f16x8 qhi = *(const f16x8*)(qp + 8);
  f16x8 qlo2 = *(const f16x8*)(qp + DOF);
  f16x8 qhi2 = *(const f16x8*)(qp + DOF + 8);
  float4 q4[4];
  q4[0] = make_float4((float)qlo[0] + (float)qlo2[0], (float)qlo[1] + (float)qlo2[1],
                      (float)qlo[2] + (float)qlo2[2], (float)qlo[3] + (float)qlo2[3]);
  q4[1] = make_float4((float)qlo[4] + (float)qlo2[4], (float)qlo[5] + (float)qlo2[5],
                      (float)qlo[6] + (float)qlo2[6], (float)qlo[7] + (float)qlo2[7]);
  q4[2] = make_float4((float)qhi[0] + (float)qhi2[0], (float)qhi[1] + (float)qhi2[1],
                      (float)qhi[2] + (float)qhi2[2], (float)qhi[3] + (float)qhi2[3]);
  q4[3] = make_float4((float)qhi[4] + (float)qhi2[4], (float)qhi[5] + (float)qhi2[5],
                      (float)qhi[6] + (float)qhi2[6], (float)qhi[7] + (float)qhi2[7]);

  const f16* kbase = kh + ((size_t)(bh * kS + kvc * 64)) * kDH;
  const f16* vbase = vh + ((size_t)(bh * kS + kvc * 64)) * kDH;
#pragma unroll
  for (int it = 0; it < 2; it++) {
    int flat = it * 256 + tid;          // 512 chunks of 8 f16
    int row = flat >> 3, c8 = flat & 7;
    f16x8 kv8  = *(const f16x8*)(kbase + (size_t)row * kDH + c8 * 8);
    f16x8 kv8b = *(const f16x8*)(kbase + DOF + (size_t)row * kDH + c8 * 8);
    f16x8 vv8  = *(const f16x8*)(vbase + (size_t)row * kDH + c8 * 8);
    f16x8 vv8b = *(const f16x8*)(vbase + DOF + (size_t)row * kDH + c8 * 8);
    Ks4[row][c8 * 2]     = make_float4((float)kv8[0] + (float)kv8b[0], (float)kv8[1] + (float)kv8b[1],
                                       (float)kv8[2] + (float)kv8b[2], (float)kv8[3] + (float)kv8b[3]);
    Ks4[row][c8 * 2 + 1] = make_float4((float)kv8[4] + (float)kv8b[4], (float)kv8[5] + (float)kv8b[5],
                                       (float)kv8[6] + (float)kv8b[6], (float)kv8[7] + (float)kv8b[7]);
    Vs4[row][c8 * 2]     = make_float4((float)vv8[0] + (float)vv8b[0], (float)vv8[1] + (float)vv8b[1],
                                       (float)vv8[2] + (float)vv8b[2], (float)vv8[3] + (float)vv8b[3]);
    Vs4[row][c8 * 2 + 1] = make_float4((float)vv8[4] + (float)vv8b[4], (float)vv8[5] + (float)vv8b[5],
                                       (float)vv8[6] + (float)vv8b[6], (float)vv8[7] + (float)vv8b[7]);
  }
  __syncthreads();

  float p[64];
#pragma unroll
  for (int kk = 0; kk < 64; kk++) {
    float4 acc;
    acc.x = acc.y = acc.z = acc.w = 0.f;
#pragma unroll
    for (int i = 0; i < 4; i++) {
      float4 kv = Ks4[kk][part * 4 + i];
      acc.x += q4[i].x * kv.x;
      acc.y += q4[i].y * kv.y;
      acc.z += q4[i].z * kv.z;
      acc.w += q4[i].w * kv.w;
    }
    float d = (acc.x + acc.y) + (acc.z + acc.w);
    d += __shfl_xor(d, 1, 64);
    d += __shfl_xor(d, 2, 64);
    p[kk] = d * 0.125f;
  }

  float mc = -INFINITY;
#pragma unroll
  for (int kk = 0; kk < 64; kk++) mc = fmaxf(mc, p[kk]);
  float l = 0.f;
#pragma unroll
  for (int kk = 0; kk < 64; kk++) {
    p[kk] = __expf(p[kk] - mc);
    l += p[kk];
  }

  float4 ctx4[4];
#pragma unroll
  for (int i = 0; i < 4; i++) { ctx4[i].x = ctx4[i].y = ctx4[i].z = ctx4[i].w = 0.f; }
#pragma unroll
  for (int kk = 0; kk < 64; kk++) {
    float pv = p[kk];
#pragma unroll
    for (int i = 0; i < 4; i++) {
      float4 vv = Vs4[kk][part * 4 + i];
      ctx4[i].x += pv * vv.x;
      ctx4[i].y += pv * vv.y;
      ctx4[i].z += pv * vv.z;
      ctx4[i].w += pv * vv.w;
    }
  }

  int tok = bb * kS + qg;
  f16* dst = ctxP + (size_t)kvc * kMH + (size_t)tok * kH + hh * kDH + part * 16;
  f16x8 o0, o1;
  o0[0] = (f16)ctx4[0].x; o0[1] = (f16)ctx4[0].y; o0[2] = (f16)ctx4[0].z; o0[3] = (f16)ctx4[0].w;
  o0[4] = (f16)ctx4[1].x; o0[5] = (f16)ctx4[1].y; o0[6] = (f16)ctx4[1].z; o0[7] = (f16)ctx4[1].w;
  o1[0] = (f16)ctx4[2].x; o1[1] = (f16)ctx4[2].y; o1[2] = (f16)ctx4[2].z; o1[3] = (f16)ctx4[2].w;
  o1[4] = (f16)ctx4[3].x; o1[5] = (f16)ctx4[3].y; o1[6] = (f16)ctx4[3].z; o1[7] = (f16)ctx4[3].w;
  *(f16x8*)dst = o0;
  *(f16x8*)(dst + 8) = o1;
  if (part == 0) {
    int mi = ((kvc * (kB * kNH) + bh) * 4 + qtb) * 64 + q;
    mlM[mi] = mc;
    mlL[mi] = l;
  }
}

// ---------------------------------------------------------------------------
// Split-KV flash attention, stage 2 (merge). One block per token; f16 out.
// ---------------------------------------------------------------------------
__global__ __launch_bounds__(256) void attn_merge_kernel(
    const f16* __restrict__ ctxP, const float* __restrict__ mlM,
    const float* __restrict__ mlL, f16* __restrict__ oH) {
  int tok = blockIdx.x;
  int tid = threadIdx.x;
  int b = tok >> 8, s = tok & 255;
  int qtb = s >> 6, q = s & 63;
  __shared__ float lm[kNH * 4], ll[kNH * 4], wts[kNH * 4];
  if (tid < kNH * 4) {
    int h = tid >> 2, kvc = tid & 3;
    int mi = ((kvc * (kB * kNH) + (b * kNH + h)) * 4 + qtb) * 64 + q;
    lm[tid] = mlM[mi];
    ll[tid] = mlL[mi];
  }
  __syncthreads();
  if (tid < kNH) {
    int h4 = tid * 4;
    float M = fmaxf(fmaxf(lm[h4], lm[h4 + 1]), fmaxf(lm[h4 + 2], lm[h4 + 3]));
    float w0 = __expf(lm[h4] - M),     w1 = __expf(lm[h4 + 1] - M);
    float w2 = __expf(lm[h4 + 2] - M), w3 = __expf(lm[h4 + 3] - M);
    float inv = 1.f / (ll[h4] * w0 + ll[h4 + 1] * w1 + ll[h4 + 2] * w2 + ll[h4 + 3] * w3);
    wts[h4]     = w0 * inv;
    wts[h4 + 1] = w1 * inv;
    wts[h4 + 2] = w2 * inv;
    wts[h4 + 3] = w3 * inv;
  }
  __syncthreads();
#pragma unroll
  for (int j = 0; j < 3; ++j) {
    int c = tid + j * 256;
    int h = c >> 6;
    size_t base = (size_t)tok * kH + c;
    float v = (float)ctxP[base] * wts[h * 4]
            + (float)ctxP[kMH + base] * wts[h * 4 + 1]
            + (float)ctxP[2 * kMH + base] * wts[h * 4 + 2]
            + (float)ctxP[3 * kMH + base] * wts[h * 4 + 3];
    oH[base] = (f16)v;
  }
}

// ---------------------------------------------------------------------------
// CRF: wave-per-batch, linear-space recurrence (renorm every 8 steps).
// ---------------------------------------------------------------------------
__global__ __launch_bounds__(512) void crf_kernel(
    const float* __restrict__ em, const int* __restrict__ target,
    const float* __restrict__ start_, const float* __restrict__ end_,
    const float* __restrict__ trans_, float* __restrict__ out) {
  __shared__ int tgs[kB * kS];
  __shared__ float tr_s[kC * kC];
  __shared__ float st_s[kC], en_s[kC];
  __shared__ float red[kB];
  int tid = threadIdx.x;
  for (int i = tid; i < kB * kS; i += 512) tgs[i] = target[i];
  if (tid < kC * kC) tr_s[tid] = trans_[tid];
  if (tid < kC) { st_s[tid] = start_[tid]; en_s[tid] = end_[tid]; }
  __syncthreads();

  int wv = tid >> 6, lane = tid & 63;
  int b = wv;
  int c = (lane < kC) ? lane : 0;
  const float* emb = em + (size_t)b * kS * kC;
  const int* tg = tgs + b * kS;

  float trc[kC];
#pragma unroll
  for (int p = 0; p < kC; ++p) trc[p] = __expf(tr_s[p * kC + c]);

  float logoff = 0.f;
  float alpha = __expf(st_s[c] + emb[c]);

  for (int i = 1; i < kS; ++i) {
    float Ei = __expf(emb[(size_t)i * kC + c]);
    float av[kC];
#pragma unroll
    for (int p = 0; p < kC; ++p) av[p] = __shfl(alpha, p, 64);
    float s01 = av[0] * trc[0] + av[1] * trc[1];
    float s23 = av[2] * trc[2] + av[3] * trc[3];
    float s45 = av[4] * trc[4] + av[5] * trc[5];
    float s67 = av[6] * trc[6] + av[7] * trc[7];
    float ssum = ((s01 + s23) + (s45 + s67)) + av[8] * trc[8];
    float nxt = ssum * Ei;
    alpha = (tg[i] > -1) ? nxt : alpha;
    if ((i & 7) == 0) {
      float mx = alpha;
#pragma unroll
      for (int o = 1; o < 64; o <<= 1) mx = fmaxf(mx, __shfl_xor(mx, o, 64));
      alpha *= (1.0f / mx);
      logoff += __logf(mx);
    }
  }

  float val = (lane < kC) ? alpha * __expf(en_s[c]) : 0.f;
#pragma unroll
  for (int o = 1; o < 64; o <<= 1) val += __shfl_xor(val, o, 64);
  float den = logoff + __logf(val);

  float nsum = 0.f;
  int cnt = 0;
  for (int i = lane; i < kS; i += 64) {
    int ti = tg[i];
    if (ti > -1) {
      cnt++;
      if (i > 0) {
        int tpv = tg[i - 1];
        int tp = (tpv > -1) ? tpv : 0;
        nsum += tr_s[tp * kC + ti] + emb[(size_t)i * kC + ti];
      }
    }
  }
#pragma unroll
  for (int o = 32; o > 0; o >>= 1) {
    nsum += __shfl_down(nsum, o, 64);
    cnt  += __shfl_down(cnt, o, 64);
  }
  if (lane == 0) {
    int t0 = (tg[0] > -1) ? tg[0] : 0;
    int se = (cnt > 0) ? cnt - 1 : 0;
    int lastTag = tg[se];
    if (lastTag < 0) lastTag = 0;
    float num = st_s[t0] + emb[t0] + nsum + en_s[lastTag];
    red[b] = num - den;
  }
  __syncthreads();
  if (tid == 0) {
    float s = 0.f;
    for (int i = 0; i < kB; ++i) s += red[i];
    out[0] = -s / kB;
  }
}

// ---------------------------------------------------------------------------
extern "C" void kernel_launch(void* const* d_in, const int* in_sizes, int n_in,
                              void* d_out, int out_size, void* d_ws, size_t ws_size,
                              hipStream_t stream) {
  const int* x      = (const int*)d_in[0];
  const int* target = (const int*)d_in[1];
  const float* word_emb   = (const float*)d_in[2];
  const float* pos_emb    = (const float*)d_in[3];
  const float* type_emb   = (const float*)d_in[4];
  const float* emb_ln_w   = (const float*)d_in[5];
  const float* emb_ln_b   = (const float*)d_in[6];
  const float* qkv_w      = (const float*)d_in[7];
  const float* qkv_b      = (const float*)d_in[8];
  const float* attn_out_w = (const float*)d_in[9];
  const float* attn_out_b = (const float*)d_in[10];
  const float* attn_ln_w  = (const float*)d_in[11];
  const float* attn_ln_b  = (const float*)d_in[12];
  const float* ffn_w1     = (const float*)d_in[13];
  const float* ffn_b1     = (const float*)d_in[14];
  const float* ffn_w2     = (const float*)d_in[15];
  const float* ffn_b2     = (const float*)d_in[16];
  const float* ffn_ln_w   = (const float*)d_in[17];
  const float* ffn_ln_b   = (const float*)d_in[18];
  const float* cls_w      = (const float*)d_in[19];
  const float* cls_b      = (const float*)d_in[20];
  const float* crf_start  = (const float*)d_in[21];
  const float* crf_end    = (const float*)d_in[22];
  const float* crf_trans  = (const float*)d_in[23];

  // ---- workspace layout (bytes) ----
  // h fp32 | hH f16 | R: qkvH DUAL (6 slabs f16, 18.87MB; f1H aliases) |
  // tbH f16 | o2H f16 (4 slabs, also ctxP) | em | ml | Wc tiled f16 | flag
  constexpr size_t offH  = 0;
  constexpr size_t offHH = 6291456;
  constexpr size_t offR  = 9437184;
  constexpr size_t offTB = offR + 6 * kMH * 2;      // 28,311,552
  constexpr size_t offO2 = offTB + kMH * 2;         // 31,457,280
  constexpr size_t offEm = offO2 + 4 * kMH * 2;     // 44,040,192
  constexpr size_t offML = offEm + 73728;           // 44,113,920
  constexpr size_t mlCnt = 4 * (size_t)(kB * kNH) * 4 * 64;   // 98,304
  constexpr size_t offW  = offML + 2 * mlCnt * 4;   // 44,900,352
  constexpr size_t wcBytes = (size_t)kNL * kLStride * 2;  // 169,869,312
  constexpr size_t offFlag = offW + wcBytes;        // 214,769,664
  constexpr size_t needA = offFlag + 64;            // ~214.8 MB

  bool cacheW = ws_size >= needA;

  char* W = (char*)d_ws;
  float* h   = (float*)(W + offH);
  f16*   hH  = (f16*)(W + offHH);
  f16*   qkvH = (f16*)(W + offR);
  f16*   tbH = (f16*)(W + offTB);
  f16*   f1H = (f16*)(W + offR);
  f16*   o2H = (f16*)(W + offO2);
  float* em  = (float*)(W + offEm);
  float* mlM = (float*)(W + offML);
  float* mlL = mlM + mlCnt;
  f16*   Wc  = (f16*)(W + offW);
  unsigned* flag = (unsigned*)(W + offFlag);

  if (cacheW) {
    wconv_mega<<<2048, 256, 0, stream>>>(qkv_w, attn_out_w, ffn_w1, ffn_w2,
                                         Wc, flag, 0, kNL);
    setflag_kernel<<<1, 1, 0, stream>>>(flag);
  }

  embed_ln_kernel<<<kM, 256, 0, stream>>>(x, word_emb, pos_emb, type_emb,
                                          emb_ln_w, emb_ln_b, h, hH);

  for (int l = 0; l < kNL; l++) {
    if (!cacheW) {
      wconv_mega<<<1024, 256, 0, stream>>>(qkv_w, attn_out_w, ffn_w1, ffn_w2,
                                           Wc, nullptr, l, 1);
    }
    f16* base = cacheW ? Wc + (size_t)l * kLStride : Wc;
    f16* wQKV = base;
    f16* wAO  = base + 3 * kHH;
    f16* wF1  = base + 4 * kHH;
    f16* wF2  = base + 4 * kHH + kHF;

    // ---- QKV: TN=64, z = 3 matrices x 2 k-chunks = 6 (1152 blocks, 4.5/CU);
    //      dual f16 head-major slabs, summed inside attention ----
    gemm_mfma<1, 64><<<dim3(12, 16, 6), 256, 0, stream>>>(
        hH, wQKV, qkv_b + (size_t)l * 3 * kH, qkvH, kH, kH);
    // ---- attention: split-KV f16 partials into o2H, then merge ----
    attn_part_kernel<<<dim3(kB * kNH, 4, 4), 256, 0, stream>>>(
        qkvH, qkvH + kMH, qkvH + 2 * kMH, o2H, mlM, mlL);
    attn_merge_kernel<<<kM, 256, 0, stream>>>(o2H, mlM, mlL, tbH);
    // ---- attn out: TN=64, split-K 4 (768 blocks = 3/CU) ----
    gemm_mfma<2, 64><<<dim3(12, 16, 4), 256, 0, stream>>>(
        tbH, wAO, attn_out_b + l * kH, o2H, kH, kH);
    addln_kernel<4, 0><<<kM, 256, 0, stream>>>(
        h, o2H, attn_ln_w + l * kH, attn_ln_b + l * kH, h, hH,
        nullptr, nullptr, nullptr);
    // ---- FFN1: TN=64, GELU -> f16 (768 blocks = 3/CU) ----
    gemm_mfma<0, 64><<<dim3(48, 16, 1), 256, 0, stream>>>(
        hH, wF1, ffn_b1 + (size_t)l * kFF, f1H, kFF, kH);
    // ---- FFN2: TN=64, split-K 4 (768 blocks = 3/CU) ----
    gemm_mfma<2, 64><<<dim3(12, 16, 4), 256, 0, stream>>>(
        f1H, wF2, ffn_b2 + l * kH, o2H, kH, kFF);
    if (l == kNL - 1) {
      addln_kernel<4, 1><<<kM, 256, 0, stream>>>(
          h, o2H, ffn_ln_w + l * kH, ffn_ln_b + l * kH, h, hH,
          cls_w, cls_b, em);
    } else {
      addln_kernel<4, 0><<<kM, 256, 0, stream>>>(
          h, o2H, ffn_ln_w + l * kH, ffn_ln_b + l * kH, h, hH,
          nullptr, nullptr, nullptr);
    }
  }

  crf_kernel<<<1, 512, 0, stream>>>(em, target, crf_start, crf_end, crf_trans,
                                    (float*)d_out);
}

// Round 13
// 2344.539 us; speedup vs baseline: 1.0903x; 1.0903x over previous
//
#include <hip/hip_runtime.h>
#include <math.h>

// Problem constants
constexpr int kB  = 8;
constexpr int kS  = 256;
constexpr int kH  = 768;
constexpr int kNL = 12;
constexpr int kNH = 12;
constexpr int kFF = 3072;
constexpr int kC  = 9;
constexpr int kDH = 64;
constexpr int kM  = kB * kS;   // 2048 tokens
constexpr size_t kMH = (size_t)kM * kH;      // 1,572,864
constexpr size_t kHH = (size_t)kH * kH;      // 589,824
constexpr size_t kHF = (size_t)kH * kFF;     // 2,359,296
constexpr unsigned kMagic = 0x7A3B19C5u;

typedef float f32x4 __attribute__((ext_vector_type(4)));
typedef _Float16 f16;
typedef _Float16 f16x4 __attribute__((ext_vector_type(4)));
typedef _Float16 f16x8 __attribute__((ext_vector_type(8)));

#define GLL16(gp, lp)                                                   \
  __builtin_amdgcn_global_load_lds(                                     \
      (const __attribute__((address_space(1))) void*)(gp),              \
      (__attribute__((address_space(3))) void*)(lp), 16, 0, 0)

// ---------------------------------------------------------------------------
// Fused embedding + LayerNorm: h = LN(we[x]+pe+te); emits fp32 + fp16 plane.
// ---------------------------------------------------------------------------
__global__ __launch_bounds__(256) void embed_ln_kernel(
    const int* __restrict__ x, const float* __restrict__ we,
    const float* __restrict__ pe, const float* __restrict__ te,
    const float* __restrict__ w, const float* __restrict__ b,
    float* __restrict__ hout, f16* __restrict__ hHf) {
  int tok = blockIdx.x, tid = threadIdx.x;
  int wid = x[tok];
  int sI = tok & (kS - 1);
  __shared__ float red[8];
  float vals[3];
  float s = 0.f, s2 = 0.f;
#pragma unroll
  for (int j = 0; j < 3; j++) {
    int c = tid + j * 256;
    float v = we[(size_t)wid * kH + c] + pe[sI * kH + c] + te[c];
    vals[j] = v;
    s += v; s2 += v * v;
  }
#pragma unroll
  for (int o = 32; o > 0; o >>= 1) {
    s  += __shfl_down(s, o, 64);
    s2 += __shfl_down(s2, o, 64);
  }
  int lane = tid & 63, wv = tid >> 6;
  if (lane == 0) { red[wv] = s; red[4 + wv] = s2; }
  __syncthreads();
  float sum   = red[0] + red[1] + red[2] + red[3];
  float sumsq = red[4] + red[5] + red[6] + red[7];
  float mean = sum / kH;
  float var  = sumsq / kH - mean * mean;
  float inv  = rsqrtf(var + 1e-12f);
#pragma unroll
  for (int j = 0; j < 3; j++) {
    int c = tid + j * 256;
    float ov = (vals[j] - mean) * inv * w[c] + b[c];
    hout[(size_t)tok * kH + c] = ov;
    hHf[(size_t)tok * kH + c] = (f16)ov;
  }
}

// ---------------------------------------------------------------------------
// Fused residual(P f16 partial slabs) + LayerNorm; emits fp32 + fp16 plane.
// EMIS=1: also computes emissions em[tok][9] = LN_out . cls_w + cls_b.
// ---------------------------------------------------------------------------
template <int P, int EMIS>
__global__ __launch_bounds__(256) void addln_kernel(
    const float* __restrict__ hin, const f16* __restrict__ res,
    const float* __restrict__ w, const float* __restrict__ b,
    float* __restrict__ hout, f16* __restrict__ hHf,
    const float* __restrict__ cw, const float* __restrict__ cb,
    float* __restrict__ em) {
  int tok = blockIdx.x, tid = threadIdx.x;
  __shared__ float red[8];
  __shared__ float redE[4 * kC];
  float vals[3];
  float s = 0.f, s2 = 0.f;
#pragma unroll
  for (int j = 0; j < 3; j++) {
    int c = tid + j * 256;
    float v = hin[(size_t)tok * kH + c];
#pragma unroll
    for (int p = 0; p < P; p++) v += (float)res[p * kMH + (size_t)tok * kH + c];
    vals[j] = v;
    s += v; s2 += v * v;
  }
#pragma unroll
  for (int o = 32; o > 0; o >>= 1) {
    s  += __shfl_down(s, o, 64);
    s2 += __shfl_down(s2, o, 64);
  }
  int lane = tid & 63, wv = tid >> 6;
  if (lane == 0) { red[wv] = s; red[4 + wv] = s2; }
  __syncthreads();
  float sum   = red[0] + red[1] + red[2] + red[3];
  float sumsq = red[4] + red[5] + red[6] + red[7];
  float mean = sum / kH;
  float var  = sumsq / kH - mean * mean;
  float inv  = rsqrtf(var + 1e-12f);
  float acc9[EMIS ? kC : 1];
  if (EMIS) {
#pragma unroll
    for (int c = 0; c < kC; ++c) acc9[c] = 0.f;
  }
#pragma unroll
  for (int j = 0; j < 3; j++) {
    int c = tid + j * 256;
    float ov = (vals[j] - mean) * inv * w[c] + b[c];
    hout[(size_t)tok * kH + c] = ov;
    hHf[(size_t)tok * kH + c] = (f16)ov;
    if (EMIS) {
#pragma unroll
      for (int cls = 0; cls < kC; ++cls) acc9[cls] += ov * cw[c * kC + cls];
    }
  }
  if (EMIS) {
#pragma unroll
    for (int cls = 0; cls < kC; ++cls) {
      float v = acc9[cls];
#pragma unroll
      for (int o = 32; o > 0; o >>= 1) v += __shfl_down(v, o, 64);
      if (lane == 0) redE[wv * kC + cls] = v;
    }
    __syncthreads();
    if (tid < kC) {
      em[(size_t)tok * kC + tid] = redE[tid] + redE[kC + tid] +
                                   redE[2 * kC + tid] + redE[3 * kC + tid] +
                                   cb[tid];
    }
  }
}

// ---------------------------------------------------------------------------
// Weight conversion into TILED cache:
// cache[kt][n][p*8+j] = W[kt*32+(p^s(n))*8+j][n], s(n) = (n>>1)&3.
// ---------------------------------------------------------------------------
constexpr size_t kLStride = 4 * kHH + 2 * kHF;   // 7,077,888 f16

struct WTile {
  const float* src;
  f16* dd;
  int N, kt, n0;
};

__device__ __forceinline__ void wc_resolve(
    int tt, int l0, const float* qkv_w, const float* aow,
    const float* f1w, const float* f2w, f16* wc, WTile& ti) {
  const int perLayer = 3456;   // 864 qkv + 288 attn + 1152 ffn1 + 1152 ffn2
  int li = tt / perLayer, r = tt % perLayer;
  int l = l0 + li;
  f16* base = wc + (size_t)li * kLStride;
  int tn;
  if (r < 864) {
    int m = r / 288; tn = r % 288; ti.N = kH;
    ti.src = qkv_w + ((size_t)l * 3 + m) * kHH;
    ti.dd = base + (size_t)m * kHH;
  } else if (r < 1152) {
    tn = r - 864; ti.N = kH;
    ti.src = aow + (size_t)l * kHH;
    ti.dd = base + 3 * kHH;
  } else if (r < 2304) {
    tn = r - 1152; ti.N = kFF;
    ti.src = f1w + (size_t)l * kHF;
    ti.dd = base + 4 * kHH;
  } else {
    tn = r - 2304; ti.N = kH;
    ti.src = f2w + (size_t)l * kHF;
    ti.dd = base + 4 * kHH + kHF;
  }
  int ntile = ti.N >> 6;
  ti.kt = tn / ntile;
  ti.n0 = (tn % ntile) * 64;
}

__global__ __launch_bounds__(256) void wconv_mega(
    const float* __restrict__ qkv_w, const float* __restrict__ aow,
    const float* __restrict__ f1w, const float* __restrict__ f2w,
    f16* __restrict__ wc, const unsigned* __restrict__ flag,
    int l0, int nl) {
  if (flag && flag[0] == kMagic) return;
  __shared__ float tb[2][32 * 64];   // two linear [32][64] fp32 tiles (16 KB)
  int tid = threadIdx.x;
  int lane = tid & 63, w = tid >> 6;
  int total = nl * 3456;
  int tt = blockIdx.x;
  if (tt >= total) return;
  int G = gridDim.x;

  auto issue = [&](const WTile& ti, int buf) {
#pragma unroll
    for (int sub = 0; sub < 2; ++sub) {
      int u = w * 2 + sub;
      const float* gp = ti.src +
          (size_t)(ti.kt * 32 + u * 4 + (lane >> 4)) * ti.N +
          ti.n0 + (lane & 15) * 4;
      GLL16(gp, &tb[buf][u * 256]);
    }
  };

  WTile cur;
  wc_resolve(tt, l0, qkv_w, aow, f1w, f2w, wc, cur);
  issue(cur, 0);
  int bufc = 0;

  while (true) {
    int ttn = tt + G;
    bool has = ttn < total;
    WTile nxt;
    if (has) {
      wc_resolve(ttn, l0, qkv_w, aow, f1w, f2w, wc, nxt);
      issue(nxt, bufc ^ 1);                 // next tile's loads stay in flight
      asm volatile("s_waitcnt vmcnt(2)" ::: "memory");   // cur's 2 loads done
    } else {
      asm volatile("s_waitcnt vmcnt(0)" ::: "memory");
    }
    __builtin_amdgcn_s_barrier();           // all waves' cur-tile LDS visible
    __builtin_amdgcn_sched_barrier(0);

    {
      int n = tid >> 2, p = tid & 3;
      int s = ((cur.n0 + n) >> 1) & 3;
      int cg = p ^ s;
      f16x8 hv;
#pragma unroll
      for (int j = 0; j < 8; ++j) hv[j] = (f16)tb[bufc][(cg * 8 + j) * 64 + n];
      *(f16x8*)(cur.dd + (size_t)cur.kt * cur.N * 32 +
                (size_t)(cur.n0 + n) * 32 + p * 8) = hv;
    }
    __builtin_amdgcn_sched_barrier(0);
    __builtin_amdgcn_s_barrier();           // emit done before buf reuse
    if (!has) break;
    cur = nxt;
    bufc ^= 1;
    tt = ttn;
  }
}

__global__ void setflag_kernel(unsigned* flag) { flag[0] = kMagic; }

// ---------------------------------------------------------------------------
// fp16 MFMA GEMM (round-7 verified single-buffer structure).
// MODE 0: + GELU, f16 out [M][N].
// MODE 1: z = matrix index (qkv); f16 head-major out slab z*kMH.
// MODE 2: split-K P=gridDim.z; f16 partial slab z*kMH; bias at z==0.
// ---------------------------------------------------------------------------
template <int MODE, int TN>
__global__ __launch_bounds__(256) void gemm_mfma(
    const f16* __restrict__ Af, const f16* __restrict__ W0,
    const float* __restrict__ bias0, f16* __restrict__ outH, int N, int K) {
  constexpr int FN = TN / 32;
  int bx = blockIdx.x, by = blockIdx.y, bz = blockIdx.z;
  const f16* Bf = W0;
  const float* bias = bias0;
  int kt0 = 0, ksteps = K >> 5;
  f16* oH = outH;
  if (MODE == 1) {
    Bf = W0 + (size_t)bz * K * N;
    bias = bias0 + bz * N;
    oH = outH + (size_t)bz * kMH;
  } else if (MODE == 2) {
    int P = gridDim.z;
    ksteps = (K >> 5) / P;
    kt0 = bz * ksteps;
    oH = outH + (size_t)bz * kMH;
    if (bz != 0) bias = nullptr;
  }

  __shared__ f16 ldsA[128 * 32];
  __shared__ f16 ldsB[TN * 32];

  int tid = threadIdx.x;
  int w = tid >> 6, lane = tid & 63;
  int wm = w >> 1, wn = w & 1;

  f32x4 acc[4][FN] = {};

  for (int kt = 0; kt < ksteps; ++kt) {
    int ktAbs = kt0 + kt;
    int kbase = ktAbs * 32;
#pragma unroll
    for (int sub = 0; sub < 2; ++sub) {
      int uu = w * 2 + sub;
      int r = uu * 16 + (lane >> 2);
      int p = lane & 3;
      int c = p ^ ((r >> 1) & 3);
      const f16* gp = Af + (size_t)(by * 128 + r) * K + kbase + c * 8;
      GLL16(gp, &ldsA[uu * 512]);
    }
#pragma unroll
    for (int sub = 0; sub < TN / 64; ++sub) {
      int uu = w * (TN / 64) + sub;
      const f16* gp = Bf + (size_t)ktAbs * N * 32 +
                      ((size_t)bx * TN + uu * 16) * 32 + lane * 8;
      GLL16(gp, &ldsB[uu * 512]);
    }
    __syncthreads();

    f16x8 bfr[FN];
#pragma unroll
    for (int fn = 0; fn < FN; ++fn) {
      int row = wn * (TN / 2) + fn * 16 + (lane & 15);
      int ch = lane >> 4;
      bfr[fn] = *(const f16x8*)&ldsB[row * 32 + (ch ^ ((row >> 1) & 3)) * 8];
    }
#pragma unroll
    for (int fm = 0; fm < 4; ++fm) {
      int row = wm * 64 + fm * 16 + (lane & 15);
      int ch = lane >> 4;
      f16x8 ah = *(const f16x8*)&ldsA[row * 32 + (ch ^ ((row >> 1) & 3)) * 8];
#pragma unroll
      for (int fn = 0; fn < FN; ++fn)
        acc[fm][fn] = __builtin_amdgcn_mfma_f32_16x16x32_f16(ah, bfr[fn], acc[fm][fn], 0, 0, 0);
    }
    __syncthreads();
  }

#pragma unroll
  for (int fm = 0; fm < 4; ++fm) {
#pragma unroll
    for (int fn = 0; fn < FN; ++fn) {
#pragma unroll
      for (int j = 0; j < 4; ++j) {
        int m = by * 128 + wm * 64 + fm * 16 + (lane >> 4) * 4 + j;
        int n = bx * TN + wn * (TN / 2) + fn * 16 + (lane & 15);
        float cv = acc[fm][fn][j];
        if (MODE == 0) {
          cv += bias[n];
          float inner = 0.7978845608028654f * (cv + 0.044715f * cv * cv * cv);
          cv = 0.5f * cv * (1.0f + tanhf(inner));
          oH[(size_t)m * N + n] = (f16)cv;
        } else if (MODE == 1) {
          cv += bias[n];
          int b = m >> 8, s = m & 255, hd = n >> 6, dh = n & 63;
          oH[((size_t)(b * kNH + hd) * kS + s) * kDH + dh] = (f16)cv;
        } else {
          if (bias) cv += bias[n];
          oH[(size_t)m * N + n] = (f16)cv;
        }
      }
    }
  }
}

// ---------------------------------------------------------------------------
// Split-KV flash attention, stage 1 (round-9 verified). grid (96, 4, 4).
// 256 threads; K/V staged fp32 in LDS; writes UNNORMALIZED f16 partial ctx
// (token-major, slab kvc) + per-query (m, l) fp32.
// ---------------------------------------------------------------------------
__global__ __launch_bounds__(256) void attn_part_kernel(
    const f16* __restrict__ qh, const f16* __restrict__ kh,
    const f16* __restrict__ vh, f16* __restrict__ ctxP,
    float* __restrict__ mlM, float* __restrict__ mlL) {
  int bh = blockIdx.x;            // 0..95
  int qtb = blockIdx.y;           // 0..3
  int kvc = blockIdx.z;           // 0..3
  int bb = bh / kNH, hh = bh % kNH;
  int tid = threadIdx.x;
  int part = tid & 3;
  int q = tid >> 2;
  int qg = qtb * 64 + q;

  __shared__ float4 Ks4[64][16];
  __shared__ float4 Vs4[64][16];

  const f16* qp = qh + ((size_t)(bh * kS + qg)) * kDH + part * 16;
  f16x8 qlo = *(const f16x8*)qp;
  f16x8 qhi = *(const f16x8*)(qp + 8);
  float4 q4[4];
  q4[0] = make_float4((float)qlo[0], (float)qlo[1], (float)qlo[2], (float)qlo[3]);
  q4[1] = make_float4((float)qlo[4], (float)qlo[5], (float)qlo[6], (float)qlo[7]);
  q4[2] = make_float4((float)qhi[0], (float)qhi[1], (float)qhi[2], (float)qhi[3]);
  q4[3] = make_float4((float)qhi[4], (float)qhi[5], (float)qhi[6], (float)qhi[7]);

  const f16* kbase = kh + ((size_t)(bh * kS + kvc * 64)) * kDH;
  const f16* vbase = vh + ((size_t)(bh * kS + kvc * 64)) * kDH;
#pragma unroll
  for (int it = 0; it < 2; it++) {
    int flat = it * 256 + tid;          // 512 chunks of 8 f16
    int row = flat >> 3, c8 = flat & 7;
    f16x8 kv8 = *(const f16x8*)(kbase + (size_t)row * kDH + c8 * 8);
    f16x8 vv8 = *(const f16x8*)(vbase + (size_t)row * kDH + c8 * 8);
    Ks4[row][c8 * 2]     = make_float4((float)kv8[0], (float)kv8[1], (float)kv8[2], (float)kv8[3]);
    Ks4[row][c8 * 2 + 1] = make_float4((float)kv8[4], (float)kv8[5], (float)kv8[6], (float)kv8[7]);
    Vs4[row][c8 * 2]     = make_float4((float)vv8[0], (float)vv8[1], (float)vv8[2], (float)vv8[3]);
    Vs4[row][c8 * 2 + 1] = make_float4((float)vv8[4], (float)vv8[5], (float)vv8[6], (float)vv8[7]);
  }
  __syncthreads();

  float p[64];
#pragma unroll
  for (int kk = 0; kk < 64; kk++) {
    float4 acc;
    acc.x = acc.y = acc.z = acc.w = 0.f;
#pragma unroll
    for (int i = 0; i < 4; i++) {
      float4 kv = Ks4[kk][part * 4 + i];
      acc.x += q4[i].x * kv.x;
      acc.y += q4[i].y * kv.y;
      acc.z += q4[i].z * kv.z;
      acc.w += q4[i].w * kv.w;
    }
    float d = (acc.x + acc.y) + (acc.z + acc.w);
    d += __shfl_xor(d, 1, 64);
    d += __shfl_xor(d, 2, 64);
    p[kk] = d * 0.125f;
  }

  float mc = -INFINITY;
#pragma unroll
  for (int kk = 0; kk < 64; kk++) mc = fmaxf(mc, p[kk]);
  float l = 0.f;
#pragma unroll
  for (int kk = 0; kk < 64; kk++) {
    p[kk] = __expf(p[kk] - mc);
    l += p[kk];
  }

  float4 ctx4[4];
#pragma unroll
  for (int i = 0; i < 4; i++) { ctx4[i].x = ctx4[i].y = ctx4[i].z = ctx4[i].w = 0.f; }
#pragma unroll
  for (int kk = 0; kk < 64; kk++) {
    float pv = p[kk];
#pragma unroll
    for (int i = 0; i < 4; i++) {
      float4 vv = Vs4[kk][part * 4 + i];
      ctx4[i].x += pv * vv.x;
      ctx4[i].y += pv * vv.y;
      ctx4[i].z += pv * vv.z;
      ctx4[i].w += pv * vv.w;
    }
  }

  int tok = bb * kS + qg;
  f16* dst = ctxP + (size_t)kvc * kMH + (size_t)tok * kH + hh * kDH + part * 16;
  f16x8 o0, o1;
  o0[0] = (f16)ctx4[0].x; o0[1] = (f16)ctx4[0].y; o0[2] = (f16)ctx4[0].z; o0[3] = (f16)ctx4[0].w;
  o0[4] = (f16)ctx4[1].x; o0[5] = (f16)ctx4[1].y; o0[6] = (f16)ctx4[1].z; o0[7] = (f16)ctx4[1].w;
  o1[0] = (f16)ctx4[2].x; o1[1] = (f16)ctx4[2].y; o1[2] = (f16)ctx4[2].z; o1[3] = (f16)ctx4[2].w;
  o1[4] = (f16)ctx4[3].x; o1[5] = (f16)ctx4[3].y; o1[6] = (f16)ctx4[3].z; o1[7] = (f16)ctx4[3].w;
  *(f16x8*)dst = o0;
  *(f16x8*)(dst + 8) = o1;
  if (part == 0) {
    int mi = ((kvc * (kB * kNH) + bh) * 4 + qtb) * 64 + q;
    mlM[mi] = mc;
    mlL[mi] = l;
  }
}

// ---------------------------------------------------------------------------
// Split-KV flash attention, stage 2 (merge). One block per token; f16 out.
// ---------------------------------------------------------------------------
__global__ __launch_bounds__(256) void attn_merge_kernel(
    const f16* __restrict__ ctxP, const float* __restrict__ mlM,
    const float* __restrict__ mlL, f16* __restrict__ oH) {
  int tok = blockIdx.x;
  int tid = threadIdx.x;
  int b = tok >> 8, s = tok & 255;
  int qtb = s >> 6, q = s & 63;
  __shared__ float lm[kNH * 4], ll[kNH * 4], wts[kNH * 4];
  if (tid < kNH * 4) {
    int h = tid >> 2, kvc = tid & 3;
    int mi = ((kvc * (kB * kNH) + (b * kNH + h)) * 4 + qtb) * 64 + q;
    lm[tid] = mlM[mi];
    ll[tid] = mlL[mi];
  }
  __syncthreads();
  if (tid < kNH) {
    int h4 = tid * 4;
    float M = fmaxf(fmaxf(lm[h4], lm[h4 + 1]), fmaxf(lm[h4 + 2], lm[h4 + 3]));
    float w0 = __expf(lm[h4] - M),     w1 = __expf(lm[h4 + 1] - M);
    float w2 = __expf(lm[h4 + 2] - M), w3 = __expf(lm[h4 + 3] - M);
    float inv = 1.f / (ll[h4] * w0 + ll[h4 + 1] * w1 + ll[h4 + 2] * w2 + ll[h4 + 3] * w3);
    wts[h4]     = w0 * inv;
    wts[h4 + 1] = w1 * inv;
    wts[h4 + 2] = w2 * inv;
    wts[h4 + 3] = w3 * inv;
  }
  __syncthreads();
#pragma unroll
  for (int j = 0; j < 3; ++j) {
    int c = tid + j * 256;
    int h = c >> 6;
    size_t base = (size_t)tok * kH + c;
    float v = (float)ctxP[base] * wts[h * 4]
            + (float)ctxP[kMH + base] * wts[h * 4 + 1]
            + (float)ctxP[2 * kMH + base] * wts[h * 4 + 2]
            + (float)ctxP[3 * kMH + base] * wts[h * 4 + 3];
    oH[base] = (f16)v;
  }
}

// ---------------------------------------------------------------------------
// CRF: wave-per-batch, linear-space recurrence (renorm every 8 steps).
// ---------------------------------------------------------------------------
__global__ __launch_bounds__(512) void crf_kernel(
    const float* __restrict__ em, const int* __restrict__ target,
    const float* __restrict__ start_, const float* __restrict__ end_,
    const float* __restrict__ trans_, float* __restrict__ out) {
  __shared__ int tgs[kB * kS];
  __shared__ float tr_s[kC * kC];
  __shared__ float st_s[kC], en_s[kC];
  __shared__ float red[kB];
  int tid = threadIdx.x;
  for (int i = tid; i < kB * kS; i += 512) tgs[i] = target[i];
  if (tid < kC * kC) tr_s[tid] = trans_[tid];
  if (tid < kC) { st_s[tid] = start_[tid]; en_s[tid] = end_[tid]; }
  __syncthreads();

  int wv = tid >> 6, lane = tid & 63;
  int b = wv;
  int c = (lane < kC) ? lane : 0;
  const float* emb = em + (size_t)b * kS * kC;
  const int* tg = tgs + b * kS;

  float trc[kC];
#pragma unroll
  for (int p = 0; p < kC; ++p) trc[p] = __expf(tr_s[p * kC + c]);

  float logoff = 0.f;
  float alpha = __expf(st_s[c] + emb[c]);

  for (int i = 1; i < kS; ++i) {
    float Ei = __expf(emb[(size_t)i * kC + c]);
    float av[kC];
#pragma unroll
    for (int p = 0; p < kC; ++p) av[p] = __shfl(alpha, p, 64);
    float s01 = av[0] * trc[0] + av[1] * trc[1];
    float s23 = av[2] * trc[2] + av[3] * trc[3];
    float s45 = av[4] * trc[4] + av[5] * trc[5];
    float s67 = av[6] * trc[6] + av[7] * trc[7];
    float ssum = ((s01 + s23) + (s45 + s67)) + av[8] * trc[8];
    float nxt = ssum * Ei;
    alpha = (tg[i] > -1) ? nxt : alpha;
    if ((i & 7) == 0) {
      float mx = alpha;
#pragma unroll
      for (int o = 1; o < 64; o <<= 1) mx = fmaxf(mx, __shfl_xor(mx, o, 64));
      alpha *= (1.0f / mx);
      logoff += __logf(mx);
    }
  }

  float val = (lane < kC) ? alpha * __expf(en_s[c]) : 0.f;
#pragma unroll
  for (int o = 1; o < 64; o <<= 1) val += __shfl_xor(val, o, 64);
  float den = logoff + __logf(val);

  float nsum = 0.f;
  int cnt = 0;
  for (int i = lane; i < kS; i += 64) {
    int ti = tg[i];
    if (ti > -1) {
      cnt++;
      if (i > 0) {
        int tpv = tg[i - 1];
        int tp = (tpv > -1) ? tpv : 0;
        nsum += tr_s[tp * kC + ti] + emb[(size_t)i * kC + ti];
      }
    }
  }
#pragma unroll
  for (int o = 32; o > 0; o >>= 1) {
    nsum += __shfl_down(nsum, o, 64);
    cnt  += __shfl_down(cnt, o, 64);
  }
  if (lane == 0) {
    int t0 = (tg[0] > -1) ? tg[0] : 0;
    int se = (cnt > 0) ? cnt - 1 : 0;
    int lastTag = tg[se];
    if (lastTag < 0) lastTag = 0;
    float num = st_s[t0] + emb[t0] + nsum + en_s[lastTag];
    red[b] = num - den;
  }
  __syncthreads();
  if (tid == 0) {
    float s = 0.f;
    for (int i = 0; i < kB; ++i) s += red[i];
    out[0] = -s / kB;
  }
}

// ---------------------------------------------------------------------------
extern "C" void kernel_launch(void* const* d_in, const int* in_sizes, int n_in,
                              void* d_out, int out_size, void* d_ws, size_t ws_size,
                              hipStream_t stream) {
  const int* x      = (const int*)d_in[0];
  const int* target = (const int*)d_in[1];
  const float* word_emb   = (const float*)d_in[2];
  const float* pos_emb    = (const float*)d_in[3];
  const float* type_emb   = (const float*)d_in[4];
  const float* emb_ln_w   = (const float*)d_in[5];
  const float* emb_ln_b   = (const float*)d_in[6];
  const float* qkv_w      = (const float*)d_in[7];
  const float* qkv_b      = (const float*)d_in[8];
  const float* attn_out_w = (const float*)d_in[9];
  const float* attn_out_b = (const float*)d_in[10];
  const float* attn_ln_w  = (const float*)d_in[11];
  const float* attn_ln_b  = (const float*)d_in[12];
  const float* ffn_w1     = (const float*)d_in[13];
  const float* ffn_b1     = (const float*)d_in[14];
  const float* ffn_w2     = (const float*)d_in[15];
  const float* ffn_b2     = (const float*)d_in[16];
  const float* ffn_ln_w   = (const float*)d_in[17];
  const float* ffn_ln_b   = (const float*)d_in[18];
  const float* cls_w      = (const float*)d_in[19];
  const float* cls_b      = (const float*)d_in[20];
  const float* crf_start  = (const float*)d_in[21];
  const float* crf_end    = (const float*)d_in[22];
  const float* crf_trans  = (const float*)d_in[23];

  // ---- workspace layout (bytes), identical to round 7/9/11 ----
  constexpr size_t offH  = 0;
  constexpr size_t offHH = 6291456;
  constexpr size_t offR  = 9437184;
  constexpr size_t offTB = offR + 3 * kMH * 2;      // 18,874,368
  constexpr size_t offO2 = offR + 12582912;         // 22,020,096
  constexpr size_t offEm = offO2 + 4 * kMH * 2;     // 34,603,008
  constexpr size_t offML = offEm + 73728;           // 34,676,736
  constexpr size_t mlCnt = 4 * (size_t)(kB * kNH) * 4 * 64;   // 98,304
  constexpr size_t offW  = offML + 2 * mlCnt * 4;   // 35,463,168
  constexpr size_t wcBytes = (size_t)kNL * kLStride * 2;  // 169,869,312
  constexpr size_t offFlag = offW + wcBytes;        // 205,332,480
  constexpr size_t needA = offFlag + 64;            // ~205.3 MB

  bool cacheW = ws_size >= needA;

  char* W = (char*)d_ws;
  float* h   = (float*)(W + offH);
  f16*   hH  = (f16*)(W + offHH);
  f16*   qkvH = (f16*)(W + offR);
  f16*   tbH = (f16*)(W + offTB);
  f16*   f1H = (f16*)(W + offR);
  f16*   o2H = (f16*)(W + offO2);
  float* em  = (float*)(W + offEm);
  float* mlM = (float*)(W + offML);
  float* mlL = mlM + mlCnt;
  f16*   Wc  = (f16*)(W + offW);
  unsigned* flag = (unsigned*)(W + offFlag);

  if (cacheW) {
    wconv_mega<<<2048, 256, 0, stream>>>(qkv_w, attn_out_w, ffn_w1, ffn_w2,
                                         Wc, flag, 0, kNL);
    setflag_kernel<<<1, 1, 0, stream>>>(flag);
  }

  embed_ln_kernel<<<kM, 256, 0, stream>>>(x, word_emb, pos_emb, type_emb,
                                          emb_ln_w, emb_ln_b, h, hH);

  for (int l = 0; l < kNL; l++) {
    if (!cacheW) {
      wconv_mega<<<1024, 256, 0, stream>>>(qkv_w, attn_out_w, ffn_w1, ffn_w2,
                                           Wc, nullptr, l, 1);
    }
    f16* base = cacheW ? Wc + (size_t)l * kLStride : Wc;
    f16* wQKV = base;
    f16* wAO  = base + 3 * kHH;
    f16* wF1  = base + 4 * kHH;
    f16* wF2  = base + 4 * kHH + kHF;

    // ---- QKV: TN=64, z = matrix; f16 head-major slabs ----
    gemm_mfma<1, 64><<<dim3(12, 16, 3), 256, 0, stream>>>(
        hH, wQKV, qkv_b + (size_t)l * 3 * kH, qkvH, kH, kH);
    // ---- attention: split-KV f16 partials into o2H, then merge ----
    attn_part_kernel<<<dim3(kB * kNH, 4, 4), 256, 0, stream>>>(
        qkvH, qkvH + kMH, qkvH + 2 * kMH, o2H, mlM, mlL);
    attn_merge_kernel<<<kM, 256, 0, stream>>>(o2H, mlM, mlL, tbH);
    // ---- attn out: TN=64, split-K 2, f16 partial slabs ----
    gemm_mfma<2, 64><<<dim3(12, 16, 2), 256, 0, stream>>>(
        tbH, wAO, attn_out_b + l * kH, o2H, kH, kH);
    addln_kernel<2, 0><<<kM, 256, 0, stream>>>(
        h, o2H, attn_ln_w + l * kH, attn_ln_b + l * kH, h, hH,
        nullptr, nullptr, nullptr);
    // ---- FFN1: TN=64, GELU -> f16 ----
    gemm_mfma<0, 64><<<dim3(48, 16, 1), 256, 0, stream>>>(
        hH, wF1, ffn_b1 + (size_t)l * kFF, f1H, kFF, kH);
    // ---- FFN2: TN=64, split-K 4, f16 partial slabs ----
    gemm_mfma<2, 64><<<dim3(12, 16, 4), 256, 0, stream>>>(
        f1H, wF2, ffn_b2 + l * kH, o2H, kH, kFF);
    if (l == kNL - 1) {
      addln_kernel<4, 1><<<kM, 256, 0, stream>>>(
          h, o2H, ffn_ln_w + l * kH, ffn_ln_b + l * kH, h, hH,
          cls_w, cls_b, em);
    } else {
      addln_kernel<4, 0><<<kM, 256, 0, stream>>>(
          h, o2H, ffn_ln_w + l * kH, ffn_ln_b + l * kH, h, hH,
          nullptr, nullptr, nullptr);
    }
  }

  crf_kernel<<<1, 512, 0, stream>>>(em, target, crf_start, crf_end, crf_trans,
                                    (float*)d_out);
}